// Round 4
// baseline (2637.646 us; speedup 1.0000x reference)
//
#include <hip/hip_runtime.h>

// Tsit5 coefficients (b7 = 0 -> 6 stages)
__device__ constexpr float cA21 = 0.161f;
__device__ constexpr float cA31 = -0.008480655492356989f, cA32 = 0.335480655492357f;
__device__ constexpr float cA41 = 2.8971530571054935f,  cA42 = -6.359448489975075f,  cA43 = 4.3622954328695815f;
__device__ constexpr float cA51 = 5.325864828439257f,   cA52 = -11.748883564062828f, cA53 = 7.4955393428898365f, cA54 = -0.09249506636175525f;
__device__ constexpr float cA61 = 5.86145544294642f,    cA62 = -12.92096931784711f,  cA63 = 8.159367898576159f,  cA64 = -0.071584973281401f, cA65 = -0.028269050394068383f;
__device__ constexpr float cB1 = 0.09646076681806523f,  cB2 = 0.01f,                 cB3 = 0.4798896504144996f;
__device__ constexpr float cB4 = 1.379008574103742f,    cB5 = -3.290069515436081f,   cB6 = 2.324710524099774f;

#define N_D 16
#define N_H 32
#define N_T 40
#define N_B 8192

// Intra-wave producer->consumer fence: LDS writes complete when lgkmcnt hits 0.
// Single-wave data exchange needs no s_barrier (lockstep wave); the "memory"
// clobber stops the compiler reordering the following ds_reads above it.
__device__ __forceinline__ void wave_fence() {
    asm volatile("s_waitcnt lgkmcnt(0)" ::: "memory");
}

__device__ __forceinline__ float softplus_f(float x) {
    // jax.nn.softplus = max(x,0) + log1p(exp(-|x|))
    float e = __expf(-fabsf(x));
    return fmaxf(x, 0.0f) + __logf(1.0f + e);
}

template <int NV>  // NV = number of float4 chunks
__device__ __forceinline__ float dotv(const float* buf, const float* w) {
    const float4* p = reinterpret_cast<const float4*>(buf);
    float a0 = 0.0f, a1 = 0.0f, a2 = 0.0f, a3 = 0.0f;
#pragma unroll
    for (int q = 0; q < NV; ++q) {
        float4 u = p[q];
        a0 = fmaf(u.x, w[4 * q + 0], a0);
        a1 = fmaf(u.y, w[4 * q + 1], a1);
        a2 = fmaf(u.z, w[4 * q + 2], a2);
        a3 = fmaf(u.w, w[4 * q + 3], a3);
    }
    return (a0 + a1) + (a2 + a3);
}

// Wave = 64 lanes = 2 trajectories x 32 neurons; each lane stores HALF of each
// weight column (its t-half of rows), computes partial dots for BOTH
// trajectories, one shfl_xor(32) completes both. 48 weight regs/lane.
// __launch_bounds__(256, 4): min 4 waves/EU -> VGPR cap 128. Round-3 evidence:
// without it the compiler targeted 8 waves/EU (cap 64, VGPR_Count=52) and
// rematerialized all 48 weight loads EVERY eval (~3x instruction bloat).
// 4 waves/EU == our exact residency (1024 blocks x 4 waves / 1024 SIMDs),
// so the cap costs nothing.
__global__ void __launch_bounds__(256, 4) ode_tsit5_kernel(
    const float* __restrict__ x0s, const float* __restrict__ t_eval,
    const float* __restrict__ W0, const float* __restrict__ b0,
    const float* __restrict__ W1, const float* __restrict__ b1,
    const float* __restrict__ W2, const float* __restrict__ b2,
    const float* __restrict__ W3, const float* __restrict__ b3,
    float* __restrict__ out)
{
    __shared__ alignas(16) float ybuf[4][2][N_D];
    __shared__ alignas(16) float Abuf[4][2][N_H];
    __shared__ alignas(16) float Bbuf[4][2][N_H];

    const int tid  = threadIdx.x;
    const int wid  = tid >> 6;
    const int lane = tid & 63;
    const int t    = lane >> 5;   // which trajectory of the wave's pair this lane's weights serve
    const int j    = lane & 31;   // neuron / column index
    const int o    = j & 15;      // output dim (layer 3) / state dim
    const int h    = j >> 4;      // which 16-row half of W3 this lane covers
    const int traj = (blockIdx.x * 4 + wid) * 2 + t;

    float (*yb)[N_D] = ybuf[wid];
    float (*Ab)[N_H] = Abuf[wid];
    float (*Bb)[N_H] = Bbuf[wid];

    // Per-lane HALF weight columns (static-indexed after unroll -> registers)
    float w0c[8], w1c[16], w2c[16], w3c[8];
#pragma unroll
    for (int i = 0; i < 8; ++i)  w0c[i] = W0[(t * 8 + i) * N_H + j];
#pragma unroll
    for (int i = 0; i < 16; ++i) w1c[i] = W1[(t * 16 + i) * N_H + j];
#pragma unroll
    for (int i = 0; i < 16; ++i) w2c[i] = W2[(t * 16 + i) * N_H + j];
#pragma unroll
    for (int i = 0; i < 8; ++i)  w3c[i] = W3[(h * 16 + t * 8 + i) * N_D + o];
    const float b0j = b0[j], b1j = b1[j], b2j = b2[j], b3o = b3[o];

    float y = x0s[traj * N_D + o];

    if (j < 16) {
        yb[t][j] = y;
        out[(size_t)traj * N_T * N_D + j] = y;  // SaveAt includes t0
    }

    // Exchange pattern: lane computes partials p0 (traj 0) and p1 (traj 1) over
    // its rows; sends the partner-trajectory partial, keeps its own, adds the
    // received complement -> full dot for trajectory t on this lane.
    auto EVAL = [&]() -> float {
        wave_fence();  // ybuf writes from previous stage visible
        // L0: D=16 -> H=32, rows [t*8, t*8+8)
        float p0 = dotv<2>(&yb[0][t * 8], w0c);
        float p1 = dotv<2>(&yb[1][t * 8], w0c);
        float send = t ? p0 : p1;
        float keep = t ? p1 : p0;
        float z = keep + __shfl_xor(send, 32, 64) + b0j;
        Ab[t][j] = softplus_f(z);
        wave_fence();
        // L1: 32 -> 32, rows [t*16, t*16+16)
        p0 = dotv<4>(&Ab[0][t * 16], w1c);
        p1 = dotv<4>(&Ab[1][t * 16], w1c);
        send = t ? p0 : p1;
        keep = t ? p1 : p0;
        z = keep + __shfl_xor(send, 32, 64) + b1j;
        Bb[t][j] = softplus_f(z);
        wave_fence();
        // L2: 32 -> 32
        p0 = dotv<4>(&Bb[0][t * 16], w2c);
        p1 = dotv<4>(&Bb[1][t * 16], w2c);
        send = t ? p0 : p1;
        keep = t ? p1 : p0;
        z = keep + __shfl_xor(send, 32, 64) + b2j;
        Ab[t][j] = softplus_f(z);
        wave_fence();
        // L3: 32 -> D=16, rows [h*16 + t*8, +8); combine t-pieces then h-pieces
        p0 = dotv<2>(&Ab[0][h * 16 + t * 8], w3c);
        p1 = dotv<2>(&Ab[1][h * 16 + t * 8], w3c);
        send = t ? p0 : p1;
        keep = t ? p1 : p0;
        float S = keep + __shfl_xor(send, 32, 64);  // my traj, both t-pieces of my h-half
        return S + __shfl_xor(S, 16, 64) + b3o;     // + other h-half (partner shares t)
    };

    for (int ti = 0; ti < N_T - 1; ++ti) {
        const float dt = (t_eval[ti + 1] - t_eval[ti]) * 0.125f;  // / N_SUB

#pragma unroll 1
        for (int s = 0; s < 8; ++s) {
            const float k1 = EVAL();
            {
                float acc = cA21 * k1;
                float ys  = fmaf(dt, acc, y);
                if (j < 16) yb[t][j] = ys;
            }
            const float k2 = EVAL();
            {
                float acc = cA31 * k1;
                acc = fmaf(cA32, k2, acc);
                float ys = fmaf(dt, acc, y);
                if (j < 16) yb[t][j] = ys;
            }
            const float k3 = EVAL();
            {
                float acc = cA41 * k1;
                acc = fmaf(cA42, k2, acc);
                acc = fmaf(cA43, k3, acc);
                float ys = fmaf(dt, acc, y);
                if (j < 16) yb[t][j] = ys;
            }
            const float k4 = EVAL();
            {
                float acc = cA51 * k1;
                acc = fmaf(cA52, k2, acc);
                acc = fmaf(cA53, k3, acc);
                acc = fmaf(cA54, k4, acc);
                float ys = fmaf(dt, acc, y);
                if (j < 16) yb[t][j] = ys;
            }
            const float k5 = EVAL();
            {
                float acc = cA61 * k1;
                acc = fmaf(cA62, k2, acc);
                acc = fmaf(cA63, k3, acc);
                acc = fmaf(cA64, k4, acc);
                acc = fmaf(cA65, k5, acc);
                float ys = fmaf(dt, acc, y);
                if (j < 16) yb[t][j] = ys;
            }
            const float k6 = EVAL();
            {
                float acc = cB1 * k1;
                acc = fmaf(cB2, k2, acc);
                acc = fmaf(cB3, k3, acc);
                acc = fmaf(cB4, k4, acc);
                acc = fmaf(cB5, k5, acc);
                acc = fmaf(cB6, k6, acc);
                y = fmaf(dt, acc, y);
                if (j < 16) yb[t][j] = y;
            }
        }
        if (j < 16) out[((size_t)traj * N_T + (ti + 1)) * N_D + j] = y;
    }
}

extern "C" void kernel_launch(void* const* d_in, const int* in_sizes, int n_in,
                              void* d_out, int out_size, void* d_ws, size_t ws_size,
                              hipStream_t stream) {
    const float* x0s    = (const float*)d_in[0];
    const float* t_eval = (const float*)d_in[1];
    const float* W0     = (const float*)d_in[2];
    const float* b0     = (const float*)d_in[3];
    const float* W1     = (const float*)d_in[4];
    const float* b1     = (const float*)d_in[5];
    const float* W2     = (const float*)d_in[6];
    const float* b2     = (const float*)d_in[7];
    const float* W3     = (const float*)d_in[8];
    const float* b3     = (const float*)d_in[9];
    float* out          = (float*)d_out;

    dim3 grid(N_B / 8);   // 4 waves/block x 2 trajectories/wave
    dim3 block(256);
    hipLaunchKernelGGL(ode_tsit5_kernel, grid, block, 0, stream,
                       x0s, t_eval, W0, b0, W1, b1, W2, b2, W3, b3, out);
}

// Round 5
// 2560.681 us; speedup vs baseline: 1.0301x; 1.0301x over previous
//
#include <hip/hip_runtime.h>

// Tsit5 coefficients (b7 = 0 -> 6 stages)
__device__ constexpr float cA21 = 0.161f;
__device__ constexpr float cA31 = -0.008480655492356989f, cA32 = 0.335480655492357f;
__device__ constexpr float cA41 = 2.8971530571054935f,  cA42 = -6.359448489975075f,  cA43 = 4.3622954328695815f;
__device__ constexpr float cA51 = 5.325864828439257f,   cA52 = -11.748883564062828f, cA53 = 7.4955393428898365f, cA54 = -0.09249506636175525f;
__device__ constexpr float cA61 = 5.86145544294642f,    cA62 = -12.92096931784711f,  cA63 = 8.159367898576159f,  cA64 = -0.071584973281401f, cA65 = -0.028269050394068383f;
__device__ constexpr float cB1 = 0.09646076681806523f,  cB2 = 0.01f,                 cB3 = 0.4798896504144996f;
__device__ constexpr float cB4 = 1.379008574103742f,    cB5 = -3.290069515436081f,   cB6 = 2.324710524099774f;

#define N_D 16
#define N_H 32
#define N_T 40
#define N_B 8192

// Intra-wave producer->consumer fence (single-wave exchange, no s_barrier needed).
__device__ __forceinline__ void wave_fence() {
    asm volatile("s_waitcnt lgkmcnt(0)" ::: "memory");
}

__device__ __forceinline__ float softplus_f(float x) {
    float e = __expf(-fabsf(x));
    return fmaxf(x, 0.0f) + __logf(1.0f + e);
}

__device__ __forceinline__ float dot8(float4 a0, float4 a1, float4 w0, float4 w1) {
    float s0 = 0.0f, s1 = 0.0f;
    s0 = fmaf(a0.x, w0.x, s0); s1 = fmaf(a0.y, w0.y, s1);
    s0 = fmaf(a0.z, w0.z, s0); s1 = fmaf(a0.w, w0.w, s1);
    s0 = fmaf(a1.x, w1.x, s0); s1 = fmaf(a1.y, w1.y, s1);
    s0 = fmaf(a1.z, w1.z, s0); s1 = fmaf(a1.w, w1.w, s1);
    return s0 + s1;
}

// Wave = 64 lanes = 2 trajectories x 32 neurons; each lane holds HALF of each
// weight column as NAMED float4s (48 VGPRs of SSA values — round-4 evidence:
// local ARRAYS passed by pointer into the dot helper failed SROA and lived in
// scratch; VGPR_Count=52 and ~4x instruction bloat at VALUBusy~100%).
__global__ void __launch_bounds__(256, 4) ode_tsit5_kernel(
    const float* __restrict__ x0s, const float* __restrict__ t_eval,
    const float* __restrict__ W0, const float* __restrict__ b0,
    const float* __restrict__ W1, const float* __restrict__ b1,
    const float* __restrict__ W2, const float* __restrict__ b2,
    const float* __restrict__ W3, const float* __restrict__ b3,
    float* __restrict__ out)
{
    __shared__ alignas(16) float ybuf[4][2][N_D];
    __shared__ alignas(16) float Abuf[4][2][N_H];
    __shared__ alignas(16) float Bbuf[4][2][N_H];

    const int tid  = threadIdx.x;
    const int wid  = tid >> 6;
    const int lane = tid & 63;
    const int t    = lane >> 5;   // trajectory whose OUTPUT this lane carries; also row-half owned
    const int j    = lane & 31;   // neuron / column index
    const int o    = j & 15;      // output dim (layer 3) / state dim
    const int h    = j >> 4;      // 16-row half of W3 covered by this lane
    const int traj = (blockIdx.x * 4 + wid) * 2 + t;

    float (*yb)[N_D] = ybuf[wid];
    float (*Ab)[N_H] = Abuf[wid];
    float (*Bb)[N_H] = Bbuf[wid];

    // Named per-lane weight fragments (rows t*8.. / t*16.. of column j)
    float4 w00, w01;            // W0 rows [t*8, t*8+8), col j
    float4 w10, w11, w12, w13;  // W1 rows [t*16, t*16+16), col j
    float4 w20, w21, w22, w23;  // W2 rows [t*16, t*16+16), col j
    float4 w30, w31;            // W3 rows [h*16+t*8, +8), col o
    {
        float v[8];
#pragma unroll
        for (int i = 0; i < 8; ++i)  v[i] = W0[(t * 8 + i) * N_H + j];
        w00 = make_float4(v[0], v[1], v[2], v[3]);
        w01 = make_float4(v[4], v[5], v[6], v[7]);
    }
    {
        float v[16];
#pragma unroll
        for (int i = 0; i < 16; ++i) v[i] = W1[(t * 16 + i) * N_H + j];
        w10 = make_float4(v[0], v[1], v[2], v[3]);
        w11 = make_float4(v[4], v[5], v[6], v[7]);
        w12 = make_float4(v[8], v[9], v[10], v[11]);
        w13 = make_float4(v[12], v[13], v[14], v[15]);
    }
    {
        float v[16];
#pragma unroll
        for (int i = 0; i < 16; ++i) v[i] = W2[(t * 16 + i) * N_H + j];
        w20 = make_float4(v[0], v[1], v[2], v[3]);
        w21 = make_float4(v[4], v[5], v[6], v[7]);
        w22 = make_float4(v[8], v[9], v[10], v[11]);
        w23 = make_float4(v[12], v[13], v[14], v[15]);
    }
    {
        float v[8];
#pragma unroll
        for (int i = 0; i < 8; ++i)  v[i] = W3[(h * 16 + t * 8 + i) * N_D + o];
        w30 = make_float4(v[0], v[1], v[2], v[3]);
        w31 = make_float4(v[4], v[5], v[6], v[7]);
    }
    const float b0j = b0[j], b1j = b1[j], b2j = b2[j], b3o = b3[o];

    float y = x0s[traj * N_D + o];

    if (j < 16) {
        yb[t][j] = y;
        out[(size_t)traj * N_T * N_D + j] = y;  // SaveAt includes t0
    }

    // Lane computes partial dots for BOTH trajectories over its row-half;
    // one shfl_xor(32) exchange completes both trajectories' dots.
    auto EVAL = [&]() -> float {
        wave_fence();
        // L0: D=16 -> H=32, rows [t*8, t*8+8)
        const float4* Y0 = reinterpret_cast<const float4*>(&yb[0][t * 8]);
        const float4* Y1 = reinterpret_cast<const float4*>(&yb[1][t * 8]);
        float4 a0 = Y0[0], a1 = Y0[1], c0 = Y1[0], c1 = Y1[1];
        float p0 = dot8(a0, a1, w00, w01);
        float p1 = dot8(c0, c1, w00, w01);
        float send = t ? p0 : p1;
        float keep = t ? p1 : p0;
        float z = keep + __shfl_xor(send, 32, 64) + b0j;
        Ab[t][j] = softplus_f(z);
        wave_fence();
        // L1: 32 -> 32, rows [t*16, t*16+16)
        const float4* A0 = reinterpret_cast<const float4*>(&Ab[0][t * 16]);
        const float4* A1 = reinterpret_cast<const float4*>(&Ab[1][t * 16]);
        float4 q0 = A0[0], q1 = A0[1], q2 = A0[2], q3 = A0[3];
        float4 r0 = A1[0], r1 = A1[1], r2 = A1[2], r3 = A1[3];
        p0 = dot8(q0, q1, w10, w11) + dot8(q2, q3, w12, w13);
        p1 = dot8(r0, r1, w10, w11) + dot8(r2, r3, w12, w13);
        send = t ? p0 : p1;
        keep = t ? p1 : p0;
        z = keep + __shfl_xor(send, 32, 64) + b1j;
        Bb[t][j] = softplus_f(z);
        wave_fence();
        // L2: 32 -> 32
        const float4* B0 = reinterpret_cast<const float4*>(&Bb[0][t * 16]);
        const float4* B1 = reinterpret_cast<const float4*>(&Bb[1][t * 16]);
        q0 = B0[0]; q1 = B0[1]; q2 = B0[2]; q3 = B0[3];
        r0 = B1[0]; r1 = B1[1]; r2 = B1[2]; r3 = B1[3];
        p0 = dot8(q0, q1, w20, w21) + dot8(q2, q3, w22, w23);
        p1 = dot8(r0, r1, w20, w21) + dot8(r2, r3, w22, w23);
        send = t ? p0 : p1;
        keep = t ? p1 : p0;
        z = keep + __shfl_xor(send, 32, 64) + b2j;
        Ab[t][j] = softplus_f(z);
        wave_fence();
        // L3: 32 -> 16, rows [h*16 + t*8, +8)
        const float4* C0 = reinterpret_cast<const float4*>(&Ab[0][h * 16 + t * 8]);
        const float4* C1 = reinterpret_cast<const float4*>(&Ab[1][h * 16 + t * 8]);
        a0 = C0[0]; a1 = C0[1]; c0 = C1[0]; c1 = C1[1];
        p0 = dot8(a0, a1, w30, w31);
        p1 = dot8(c0, c1, w30, w31);
        send = t ? p0 : p1;
        keep = t ? p1 : p0;
        float S = keep + __shfl_xor(send, 32, 64);  // both t-pieces of my h-half
        return S + __shfl_xor(S, 16, 64) + b3o;     // + other h-half
    };

    for (int ti = 0; ti < N_T - 1; ++ti) {
        const float dt = (t_eval[ti + 1] - t_eval[ti]) * 0.125f;  // / N_SUB

#pragma unroll 1
        for (int s = 0; s < 8; ++s) {
            const float k1 = EVAL();
            {
                float ys = fmaf(dt, cA21 * k1, y);
                if (j < 16) yb[t][j] = ys;
            }
            const float k2 = EVAL();
            {
                float acc = cA31 * k1;
                acc = fmaf(cA32, k2, acc);
                float ys = fmaf(dt, acc, y);
                if (j < 16) yb[t][j] = ys;
            }
            const float k3 = EVAL();
            {
                float acc = cA41 * k1;
                acc = fmaf(cA42, k2, acc);
                acc = fmaf(cA43, k3, acc);
                float ys = fmaf(dt, acc, y);
                if (j < 16) yb[t][j] = ys;
            }
            const float k4 = EVAL();
            {
                float acc = cA51 * k1;
                acc = fmaf(cA52, k2, acc);
                acc = fmaf(cA53, k3, acc);
                acc = fmaf(cA54, k4, acc);
                float ys = fmaf(dt, acc, y);
                if (j < 16) yb[t][j] = ys;
            }
            const float k5 = EVAL();
            {
                float acc = cA61 * k1;
                acc = fmaf(cA62, k2, acc);
                acc = fmaf(cA63, k3, acc);
                acc = fmaf(cA64, k4, acc);
                acc = fmaf(cA65, k5, acc);
                float ys = fmaf(dt, acc, y);
                if (j < 16) yb[t][j] = ys;
            }
            const float k6 = EVAL();
            {
                float acc = cB1 * k1;
                acc = fmaf(cB2, k2, acc);
                acc = fmaf(cB3, k3, acc);
                acc = fmaf(cB4, k4, acc);
                acc = fmaf(cB5, k5, acc);
                acc = fmaf(cB6, k6, acc);
                y = fmaf(dt, acc, y);
                if (j < 16) yb[t][j] = y;
            }
        }
        if (j < 16) out[((size_t)traj * N_T + (ti + 1)) * N_D + j] = y;
    }
}

extern "C" void kernel_launch(void* const* d_in, const int* in_sizes, int n_in,
                              void* d_out, int out_size, void* d_ws, size_t ws_size,
                              hipStream_t stream) {
    const float* x0s    = (const float*)d_in[0];
    const float* t_eval = (const float*)d_in[1];
    const float* W0     = (const float*)d_in[2];
    const float* b0     = (const float*)d_in[3];
    const float* W1     = (const float*)d_in[4];
    const float* b1     = (const float*)d_in[5];
    const float* W2     = (const float*)d_in[6];
    const float* b2     = (const float*)d_in[7];
    const float* W3     = (const float*)d_in[8];
    const float* b3     = (const float*)d_in[9];
    float* out          = (float*)d_out;

    dim3 grid(N_B / 8);   // 4 waves/block x 2 trajectories/wave
    dim3 block(256);
    hipLaunchKernelGGL(ode_tsit5_kernel, grid, block, 0, stream,
                       x0s, t_eval, W0, b0, W1, b1, W2, b2, W3, b3, out);
}

// Round 6
// 2537.376 us; speedup vs baseline: 1.0395x; 1.0092x over previous
//
#include <hip/hip_runtime.h>

// Tsit5 coefficients (b7 = 0 -> 6 stages)
__device__ constexpr float cA21 = 0.161f;
__device__ constexpr float cA31 = -0.008480655492356989f, cA32 = 0.335480655492357f;
__device__ constexpr float cA41 = 2.8971530571054935f,  cA42 = -6.359448489975075f,  cA43 = 4.3622954328695815f;
__device__ constexpr float cA51 = 5.325864828439257f,   cA52 = -11.748883564062828f, cA53 = 7.4955393428898365f, cA54 = -0.09249506636175525f;
__device__ constexpr float cA61 = 5.86145544294642f,    cA62 = -12.92096931784711f,  cA63 = 8.159367898576159f,  cA64 = -0.071584973281401f, cA65 = -0.028269050394068383f;
__device__ constexpr float cB1 = 0.09646076681806523f,  cB2 = 0.01f,                 cB3 = 0.4798896504144996f;
__device__ constexpr float cB4 = 1.379008574103742f,    cB5 = -3.290069515436081f,   cB6 = 2.324710524099774f;

#define N_D 16
#define N_H 32
#define N_T 40
#define N_B 8192

// Intra-wave producer->consumer fence (single-wave exchange, no s_barrier needed).
__device__ __forceinline__ void wave_fence() {
    asm volatile("s_waitcnt lgkmcnt(0)" ::: "memory");
}

// Kill rematerialization: an asm-defined value is opaque to the allocator's
// "cheap to re-load" heuristic. Rounds 3-5 evidence: without this, LLVM keeps
// VGPR at ~52-56 and re-issues all 48 weight loads EVERY eval (~3.2x VALU
// instruction bloat, invisible in FETCH_SIZE because weights are L1-resident).
#define PIN1(x)  asm volatile("" : "+v"(x))
#define PIN4(v)  asm volatile("" : "+v"(v.x), "+v"(v.y), "+v"(v.z), "+v"(v.w))

__device__ __forceinline__ float softplus_f(float x) {
    float e = __expf(-fabsf(x));
    return fmaxf(x, 0.0f) + __logf(1.0f + e);
}

__device__ __forceinline__ float dot8(float4 a0, float4 a1, float4 w0, float4 w1) {
    float s0 = 0.0f, s1 = 0.0f;
    s0 = fmaf(a0.x, w0.x, s0); s1 = fmaf(a0.y, w0.y, s1);
    s0 = fmaf(a0.z, w0.z, s0); s1 = fmaf(a0.w, w0.w, s1);
    s0 = fmaf(a1.x, w1.x, s0); s1 = fmaf(a1.y, w1.y, s1);
    s0 = fmaf(a1.z, w1.z, s0); s1 = fmaf(a1.w, w1.w, s1);
    return s0 + s1;
}

// Wave = 64 lanes = 2 trajectories x 32 neurons; each lane holds HALF of each
// weight column as NAMED, PINNED float4s (48 VGPRs of weights).
__global__ void __launch_bounds__(256, 4) ode_tsit5_kernel(
    const float* __restrict__ x0s, const float* __restrict__ t_eval,
    const float* __restrict__ W0, const float* __restrict__ b0,
    const float* __restrict__ W1, const float* __restrict__ b1,
    const float* __restrict__ W2, const float* __restrict__ b2,
    const float* __restrict__ W3, const float* __restrict__ b3,
    float* __restrict__ out)
{
    __shared__ alignas(16) float ybuf[4][2][N_D];
    __shared__ alignas(16) float Abuf[4][2][N_H];
    __shared__ alignas(16) float Bbuf[4][2][N_H];

    const int tid  = threadIdx.x;
    const int wid  = tid >> 6;
    const int lane = tid & 63;
    const int t    = lane >> 5;   // trajectory whose OUTPUT this lane carries; also row-half owned
    const int j    = lane & 31;   // neuron / column index
    const int o    = j & 15;      // output dim (layer 3) / state dim
    const int h    = j >> 4;      // 16-row half of W3 covered by this lane
    const int traj = (blockIdx.x * 4 + wid) * 2 + t;

    float (*yb)[N_D] = ybuf[wid];
    float (*Ab)[N_H] = Abuf[wid];
    float (*Bb)[N_H] = Bbuf[wid];

    // Named per-lane weight fragments (rows t*8.. / t*16.. of column j)
    float4 w00, w01;            // W0 rows [t*8, t*8+8), col j
    float4 w10, w11, w12, w13;  // W1 rows [t*16, t*16+16), col j
    float4 w20, w21, w22, w23;  // W2 rows [t*16, t*16+16), col j
    float4 w30, w31;            // W3 rows [h*16+t*8, +8), col o
    {
        float v[8];
#pragma unroll
        for (int i = 0; i < 8; ++i)  v[i] = W0[(t * 8 + i) * N_H + j];
        w00 = make_float4(v[0], v[1], v[2], v[3]);
        w01 = make_float4(v[4], v[5], v[6], v[7]);
    }
    {
        float v[16];
#pragma unroll
        for (int i = 0; i < 16; ++i) v[i] = W1[(t * 16 + i) * N_H + j];
        w10 = make_float4(v[0], v[1], v[2], v[3]);
        w11 = make_float4(v[4], v[5], v[6], v[7]);
        w12 = make_float4(v[8], v[9], v[10], v[11]);
        w13 = make_float4(v[12], v[13], v[14], v[15]);
    }
    {
        float v[16];
#pragma unroll
        for (int i = 0; i < 16; ++i) v[i] = W2[(t * 16 + i) * N_H + j];
        w20 = make_float4(v[0], v[1], v[2], v[3]);
        w21 = make_float4(v[4], v[5], v[6], v[7]);
        w22 = make_float4(v[8], v[9], v[10], v[11]);
        w23 = make_float4(v[12], v[13], v[14], v[15]);
    }
    {
        float v[8];
#pragma unroll
        for (int i = 0; i < 8; ++i)  v[i] = W3[(h * 16 + t * 8 + i) * N_D + o];
        w30 = make_float4(v[0], v[1], v[2], v[3]);
        w31 = make_float4(v[4], v[5], v[6], v[7]);
    }
    float b0j = b0[j], b1j = b1[j], b2j = b2[j], b3o = b3[o];

    // Pin everything ONCE: no instruction cost, kills remat/reload.
    PIN4(w00); PIN4(w01);
    PIN4(w10); PIN4(w11); PIN4(w12); PIN4(w13);
    PIN4(w20); PIN4(w21); PIN4(w22); PIN4(w23);
    PIN4(w30); PIN4(w31);
    PIN1(b0j); PIN1(b1j); PIN1(b2j); PIN1(b3o);

    float y = x0s[traj * N_D + o];

    if (j < 16) {
        yb[t][j] = y;
        out[(size_t)traj * N_T * N_D + j] = y;  // SaveAt includes t0
    }

    // Lane computes partial dots for BOTH trajectories over its row-half;
    // one shfl_xor(32) exchange completes both trajectories' dots.
    auto EVAL = [&]() -> float {
        wave_fence();
        // L0: D=16 -> H=32, rows [t*8, t*8+8)
        const float4* Y0 = reinterpret_cast<const float4*>(&yb[0][t * 8]);
        const float4* Y1 = reinterpret_cast<const float4*>(&yb[1][t * 8]);
        float4 a0 = Y0[0], a1 = Y0[1], c0 = Y1[0], c1 = Y1[1];
        float p0 = dot8(a0, a1, w00, w01);
        float p1 = dot8(c0, c1, w00, w01);
        float send = t ? p0 : p1;
        float keep = t ? p1 : p0;
        float z = keep + __shfl_xor(send, 32, 64) + b0j;
        Ab[t][j] = softplus_f(z);
        wave_fence();
        // L1: 32 -> 32, rows [t*16, t*16+16)
        const float4* A0 = reinterpret_cast<const float4*>(&Ab[0][t * 16]);
        const float4* A1 = reinterpret_cast<const float4*>(&Ab[1][t * 16]);
        float4 q0 = A0[0], q1 = A0[1], q2 = A0[2], q3 = A0[3];
        float4 r0 = A1[0], r1 = A1[1], r2 = A1[2], r3 = A1[3];
        p0 = dot8(q0, q1, w10, w11) + dot8(q2, q3, w12, w13);
        p1 = dot8(r0, r1, w10, w11) + dot8(r2, r3, w12, w13);
        send = t ? p0 : p1;
        keep = t ? p1 : p0;
        z = keep + __shfl_xor(send, 32, 64) + b1j;
        Bb[t][j] = softplus_f(z);
        wave_fence();
        // L2: 32 -> 32
        const float4* B0 = reinterpret_cast<const float4*>(&Bb[0][t * 16]);
        const float4* B1 = reinterpret_cast<const float4*>(&Bb[1][t * 16]);
        q0 = B0[0]; q1 = B0[1]; q2 = B0[2]; q3 = B0[3];
        r0 = B1[0]; r1 = B1[1]; r2 = B1[2]; r3 = B1[3];
        p0 = dot8(q0, q1, w20, w21) + dot8(q2, q3, w22, w23);
        p1 = dot8(r0, r1, w20, w21) + dot8(r2, r3, w22, w23);
        send = t ? p0 : p1;
        keep = t ? p1 : p0;
        z = keep + __shfl_xor(send, 32, 64) + b2j;
        Ab[t][j] = softplus_f(z);
        wave_fence();
        // L3: 32 -> 16, rows [h*16 + t*8, +8)
        const float4* C0 = reinterpret_cast<const float4*>(&Ab[0][h * 16 + t * 8]);
        const float4* C1 = reinterpret_cast<const float4*>(&Ab[1][h * 16 + t * 8]);
        a0 = C0[0]; a1 = C0[1]; c0 = C1[0]; c1 = C1[1];
        p0 = dot8(a0, a1, w30, w31);
        p1 = dot8(c0, c1, w30, w31);
        send = t ? p0 : p1;
        keep = t ? p1 : p0;
        float S = keep + __shfl_xor(send, 32, 64);  // both t-pieces of my h-half
        return S + __shfl_xor(S, 16, 64) + b3o;     // + other h-half
    };

    for (int ti = 0; ti < N_T - 1; ++ti) {
        const float dt = (t_eval[ti + 1] - t_eval[ti]) * 0.125f;  // / N_SUB

#pragma unroll 1
        for (int s = 0; s < 8; ++s) {
            const float k1 = EVAL();
            {
                float ys = fmaf(dt, cA21 * k1, y);
                if (j < 16) yb[t][j] = ys;
            }
            const float k2 = EVAL();
            {
                float acc = cA31 * k1;
                acc = fmaf(cA32, k2, acc);
                float ys = fmaf(dt, acc, y);
                if (j < 16) yb[t][j] = ys;
            }
            const float k3 = EVAL();
            {
                float acc = cA41 * k1;
                acc = fmaf(cA42, k2, acc);
                acc = fmaf(cA43, k3, acc);
                float ys = fmaf(dt, acc, y);
                if (j < 16) yb[t][j] = ys;
            }
            const float k4 = EVAL();
            {
                float acc = cA51 * k1;
                acc = fmaf(cA52, k2, acc);
                acc = fmaf(cA53, k3, acc);
                acc = fmaf(cA54, k4, acc);
                float ys = fmaf(dt, acc, y);
                if (j < 16) yb[t][j] = ys;
            }
            const float k5 = EVAL();
            {
                float acc = cA61 * k1;
                acc = fmaf(cA62, k2, acc);
                acc = fmaf(cA63, k3, acc);
                acc = fmaf(cA64, k4, acc);
                acc = fmaf(cA65, k5, acc);
                float ys = fmaf(dt, acc, y);
                if (j < 16) yb[t][j] = ys;
            }
            const float k6 = EVAL();
            {
                float acc = cB1 * k1;
                acc = fmaf(cB2, k2, acc);
                acc = fmaf(cB3, k3, acc);
                acc = fmaf(cB4, k4, acc);
                acc = fmaf(cB5, k5, acc);
                acc = fmaf(cB6, k6, acc);
                y = fmaf(dt, acc, y);
                if (j < 16) yb[t][j] = y;
            }
        }
        if (j < 16) out[((size_t)traj * N_T + (ti + 1)) * N_D + j] = y;
    }
}

extern "C" void kernel_launch(void* const* d_in, const int* in_sizes, int n_in,
                              void* d_out, int out_size, void* d_ws, size_t ws_size,
                              hipStream_t stream) {
    const float* x0s    = (const float*)d_in[0];
    const float* t_eval = (const float*)d_in[1];
    const float* W0     = (const float*)d_in[2];
    const float* b0     = (const float*)d_in[3];
    const float* W1     = (const float*)d_in[4];
    const float* b1     = (const float*)d_in[5];
    const float* W2     = (const float*)d_in[6];
    const float* b2     = (const float*)d_in[7];
    const float* W3     = (const float*)d_in[8];
    const float* b3     = (const float*)d_in[9];
    float* out          = (float*)d_out;

    dim3 grid(N_B / 8);   // 4 waves/block x 2 trajectories/wave
    dim3 block(256);
    hipLaunchKernelGGL(ode_tsit5_kernel, grid, block, 0, stream,
                       x0s, t_eval, W0, b0, W1, b1, W2, b2, W3, b3, out);
}

// Round 7
// 2507.851 us; speedup vs baseline: 1.0518x; 1.0118x over previous
//
#include <hip/hip_runtime.h>

// Tsit5 coefficients (b7 = 0 -> 6 stages)
__device__ constexpr float cA21 = 0.161f;
__device__ constexpr float cA31 = -0.008480655492356989f, cA32 = 0.335480655492357f;
__device__ constexpr float cA41 = 2.8971530571054935f,  cA42 = -6.359448489975075f,  cA43 = 4.3622954328695815f;
__device__ constexpr float cA51 = 5.325864828439257f,   cA52 = -11.748883564062828f, cA53 = 7.4955393428898365f, cA54 = -0.09249506636175525f;
__device__ constexpr float cA61 = 5.86145544294642f,    cA62 = -12.92096931784711f,  cA63 = 8.159367898576159f,  cA64 = -0.071584973281401f, cA65 = -0.028269050394068383f;
__device__ constexpr float cB1 = 0.09646076681806523f,  cB2 = 0.01f,                 cB3 = 0.4798896504144996f;
__device__ constexpr float cB4 = 1.379008574103742f,    cB5 = -3.290069515436081f,   cB6 = 2.324710524099774f;

#define N_D 16
#define N_H 32
#define N_T 40
#define N_B 8192

// Intra-wave producer->consumer fence (single-wave exchange, no s_barrier needed).
__device__ __forceinline__ void wave_fence() {
    asm volatile("s_waitcnt lgkmcnt(0)" ::: "memory");
}

// Keep loop-invariant loaded values as opaque asm results (not re-loadable).
#define PIN1(x)  asm volatile("" : "+v"(x))
#define PIN4(v)  asm volatile("" : "+v"(v.x), "+v"(v.y), "+v"(v.z), "+v"(v.w))

__device__ __forceinline__ float softplus_f(float x) {
    float e = __expf(-fabsf(x));
    return fmaxf(x, 0.0f) + __logf(1.0f + e);
}

__device__ __forceinline__ float dot8(float4 a0, float4 a1, float4 w0, float4 w1) {
    float s0 = 0.0f, s1 = 0.0f;
    s0 = fmaf(a0.x, w0.x, s0); s1 = fmaf(a0.y, w0.y, s1);
    s0 = fmaf(a0.z, w0.z, s0); s1 = fmaf(a0.w, w0.w, s1);
    s0 = fmaf(a1.x, w1.x, s0); s1 = fmaf(a1.y, w1.y, s1);
    s0 = fmaf(a1.z, w1.z, s0); s1 = fmaf(a1.w, w1.w, s1);
    return s0 + s1;
}

// Wave = 64 lanes = 2 trajectories x 32 neurons; each lane holds HALF of each
// weight column as named float4s (48 VGPRs of weights).
//
// amdgpu_waves_per_eu(4,4): rounds 3-6 evidence — __launch_bounds__'s second
// arg only sets the waves/EU MINIMUM; LLVM's occupancy heuristic still targets
// 8 waves/EU (VGPR cap 64 -> allocator chose 52-56) and re-loads all 48
// weights every eval (~3x instr bloat, L1-resident so invisible in
// FETCH_SIZE; VALUBusy>100% shows that derived counter is bogus here).
// Pinning max=4 matches our exact residency (1024 blocks x 4 waves on 1024
// SIMDs) and raises the VGPR budget to 128, making weight residency free.
__global__ void __launch_bounds__(256)
__attribute__((amdgpu_waves_per_eu(4, 4)))
ode_tsit5_kernel(
    const float* __restrict__ x0s, const float* __restrict__ t_eval,
    const float* __restrict__ W0, const float* __restrict__ b0,
    const float* __restrict__ W1, const float* __restrict__ b1,
    const float* __restrict__ W2, const float* __restrict__ b2,
    const float* __restrict__ W3, const float* __restrict__ b3,
    float* __restrict__ out)
{
    __shared__ alignas(16) float ybuf[4][2][N_D];
    __shared__ alignas(16) float Abuf[4][2][N_H];
    __shared__ alignas(16) float Bbuf[4][2][N_H];

    const int tid  = threadIdx.x;
    const int wid  = tid >> 6;
    const int lane = tid & 63;
    const int t    = lane >> 5;   // trajectory whose OUTPUT this lane carries; also row-half owned
    const int j    = lane & 31;   // neuron / column index
    const int o    = j & 15;      // output dim (layer 3) / state dim
    const int h    = j >> 4;      // 16-row half of W3 covered by this lane
    const int traj = (blockIdx.x * 4 + wid) * 2 + t;

    float (*yb)[N_D] = ybuf[wid];
    float (*Ab)[N_H] = Abuf[wid];
    float (*Bb)[N_H] = Bbuf[wid];

    // Named per-lane weight fragments (rows t*8.. / t*16.. of column j)
    float4 w00, w01;            // W0 rows [t*8, t*8+8), col j
    float4 w10, w11, w12, w13;  // W1 rows [t*16, t*16+16), col j
    float4 w20, w21, w22, w23;  // W2 rows [t*16, t*16+16), col j
    float4 w30, w31;            // W3 rows [h*16+t*8, +8), col o
    {
        float v[8];
#pragma unroll
        for (int i = 0; i < 8; ++i)  v[i] = W0[(t * 8 + i) * N_H + j];
        w00 = make_float4(v[0], v[1], v[2], v[3]);
        w01 = make_float4(v[4], v[5], v[6], v[7]);
    }
    {
        float v[16];
#pragma unroll
        for (int i = 0; i < 16; ++i) v[i] = W1[(t * 16 + i) * N_H + j];
        w10 = make_float4(v[0], v[1], v[2], v[3]);
        w11 = make_float4(v[4], v[5], v[6], v[7]);
        w12 = make_float4(v[8], v[9], v[10], v[11]);
        w13 = make_float4(v[12], v[13], v[14], v[15]);
    }
    {
        float v[16];
#pragma unroll
        for (int i = 0; i < 16; ++i) v[i] = W2[(t * 16 + i) * N_H + j];
        w20 = make_float4(v[0], v[1], v[2], v[3]);
        w21 = make_float4(v[4], v[5], v[6], v[7]);
        w22 = make_float4(v[8], v[9], v[10], v[11]);
        w23 = make_float4(v[12], v[13], v[14], v[15]);
    }
    {
        float v[8];
#pragma unroll
        for (int i = 0; i < 8; ++i)  v[i] = W3[(h * 16 + t * 8 + i) * N_D + o];
        w30 = make_float4(v[0], v[1], v[2], v[3]);
        w31 = make_float4(v[4], v[5], v[6], v[7]);
    }
    float b0j = b0[j], b1j = b1[j], b2j = b2[j], b3o = b3[o];

    PIN4(w00); PIN4(w01);
    PIN4(w10); PIN4(w11); PIN4(w12); PIN4(w13);
    PIN4(w20); PIN4(w21); PIN4(w22); PIN4(w23);
    PIN4(w30); PIN4(w31);
    PIN1(b0j); PIN1(b1j); PIN1(b2j); PIN1(b3o);

    float y = x0s[traj * N_D + o];

    if (j < 16) {
        yb[t][j] = y;
        out[(size_t)traj * N_T * N_D + j] = y;  // SaveAt includes t0
    }

    // Lane computes partial dots for BOTH trajectories over its row-half;
    // one shfl_xor(32) exchange completes both trajectories' dots.
    auto EVAL = [&]() -> float {
        wave_fence();
        // L0: D=16 -> H=32, rows [t*8, t*8+8)
        const float4* Y0 = reinterpret_cast<const float4*>(&yb[0][t * 8]);
        const float4* Y1 = reinterpret_cast<const float4*>(&yb[1][t * 8]);
        float4 a0 = Y0[0], a1 = Y0[1], c0 = Y1[0], c1 = Y1[1];
        float p0 = dot8(a0, a1, w00, w01);
        float p1 = dot8(c0, c1, w00, w01);
        float send = t ? p0 : p1;
        float keep = t ? p1 : p0;
        float z = keep + __shfl_xor(send, 32, 64) + b0j;
        Ab[t][j] = softplus_f(z);
        wave_fence();
        // L1: 32 -> 32, rows [t*16, t*16+16)
        const float4* A0 = reinterpret_cast<const float4*>(&Ab[0][t * 16]);
        const float4* A1 = reinterpret_cast<const float4*>(&Ab[1][t * 16]);
        float4 q0 = A0[0], q1 = A0[1], q2 = A0[2], q3 = A0[3];
        float4 r0 = A1[0], r1 = A1[1], r2 = A1[2], r3 = A1[3];
        p0 = dot8(q0, q1, w10, w11) + dot8(q2, q3, w12, w13);
        p1 = dot8(r0, r1, w10, w11) + dot8(r2, r3, w12, w13);
        send = t ? p0 : p1;
        keep = t ? p1 : p0;
        z = keep + __shfl_xor(send, 32, 64) + b1j;
        Bb[t][j] = softplus_f(z);
        wave_fence();
        // L2: 32 -> 32
        const float4* B0 = reinterpret_cast<const float4*>(&Bb[0][t * 16]);
        const float4* B1 = reinterpret_cast<const float4*>(&Bb[1][t * 16]);
        q0 = B0[0]; q1 = B0[1]; q2 = B0[2]; q3 = B0[3];
        r0 = B1[0]; r1 = B1[1]; r2 = B1[2]; r3 = B1[3];
        p0 = dot8(q0, q1, w20, w21) + dot8(q2, q3, w22, w23);
        p1 = dot8(r0, r1, w20, w21) + dot8(r2, r3, w22, w23);
        send = t ? p0 : p1;
        keep = t ? p1 : p0;
        z = keep + __shfl_xor(send, 32, 64) + b2j;
        Ab[t][j] = softplus_f(z);
        wave_fence();
        // L3: 32 -> 16, rows [h*16 + t*8, +8)
        const float4* C0 = reinterpret_cast<const float4*>(&Ab[0][h * 16 + t * 8]);
        const float4* C1 = reinterpret_cast<const float4*>(&Ab[1][h * 16 + t * 8]);
        a0 = C0[0]; a1 = C0[1]; c0 = C1[0]; c1 = C1[1];
        p0 = dot8(a0, a1, w30, w31);
        p1 = dot8(c0, c1, w30, w31);
        send = t ? p0 : p1;
        keep = t ? p1 : p0;
        float S = keep + __shfl_xor(send, 32, 64);  // both t-pieces of my h-half
        return S + __shfl_xor(S, 16, 64) + b3o;     // + other h-half
    };

    for (int ti = 0; ti < N_T - 1; ++ti) {
        const float dt = (t_eval[ti + 1] - t_eval[ti]) * 0.125f;  // / N_SUB

#pragma unroll 1
        for (int s = 0; s < 8; ++s) {
            const float k1 = EVAL();
            {
                float ys = fmaf(dt, cA21 * k1, y);
                if (j < 16) yb[t][j] = ys;
            }
            const float k2 = EVAL();
            {
                float acc = cA31 * k1;
                acc = fmaf(cA32, k2, acc);
                float ys = fmaf(dt, acc, y);
                if (j < 16) yb[t][j] = ys;
            }
            const float k3 = EVAL();
            {
                float acc = cA41 * k1;
                acc = fmaf(cA42, k2, acc);
                acc = fmaf(cA43, k3, acc);
                float ys = fmaf(dt, acc, y);
                if (j < 16) yb[t][j] = ys;
            }
            const float k4 = EVAL();
            {
                float acc = cA51 * k1;
                acc = fmaf(cA52, k2, acc);
                acc = fmaf(cA53, k3, acc);
                acc = fmaf(cA54, k4, acc);
                float ys = fmaf(dt, acc, y);
                if (j < 16) yb[t][j] = ys;
            }
            const float k5 = EVAL();
            {
                float acc = cA61 * k1;
                acc = fmaf(cA62, k2, acc);
                acc = fmaf(cA63, k3, acc);
                acc = fmaf(cA64, k4, acc);
                acc = fmaf(cA65, k5, acc);
                float ys = fmaf(dt, acc, y);
                if (j < 16) yb[t][j] = ys;
            }
            const float k6 = EVAL();
            {
                float acc = cB1 * k1;
                acc = fmaf(cB2, k2, acc);
                acc = fmaf(cB3, k3, acc);
                acc = fmaf(cB4, k4, acc);
                acc = fmaf(cB5, k5, acc);
                acc = fmaf(cB6, k6, acc);
                y = fmaf(dt, acc, y);
                if (j < 16) yb[t][j] = y;
            }
        }
        if (j < 16) out[((size_t)traj * N_T + (ti + 1)) * N_D + j] = y;
    }
}

extern "C" void kernel_launch(void* const* d_in, const int* in_sizes, int n_in,
                              void* d_out, int out_size, void* d_ws, size_t ws_size,
                              hipStream_t stream) {
    const float* x0s    = (const float*)d_in[0];
    const float* t_eval = (const float*)d_in[1];
    const float* W0     = (const float*)d_in[2];
    const float* b0     = (const float*)d_in[3];
    const float* W1     = (const float*)d_in[4];
    const float* b1     = (const float*)d_in[5];
    const float* W2     = (const float*)d_in[6];
    const float* b2     = (const float*)d_in[7];
    const float* W3     = (const float*)d_in[8];
    const float* b3     = (const float*)d_in[9];
    float* out          = (float*)d_out;

    dim3 grid(N_B / 8);   // 4 waves/block x 2 trajectories/wave
    dim3 block(256);
    hipLaunchKernelGGL(ode_tsit5_kernel, grid, block, 0, stream,
                       x0s, t_eval, W0, b0, W1, b1, W2, b2, W3, b3, out);
}